// Round 10
// baseline (215.602 us; speedup 1.0000x reference)
//
#include <hip/hip_runtime.h>
#include <hip/hip_bf16.h>

// out[m,e] = sum_f relu( sum_q cos(x[m,q])cos(theta[q]) w1[f,q] ) * w2[e,f]
// M=16384, E=1024, F=4096. Pipeline:
//   1) w2cvt: w2 fp32 -> bf16 once into ws
//   2) qrelu: A = relu(qv @ w1^T) bf16 into ws
//   3) gemm: out = A @ w2bf^T -- 256x256 tile, BK=64, 8 waves (2m x 4n).
//      A: LDS double-buffer (64 KiB) via global_load_lds, XOR-swizzled.
//      B: DIRECT FROM GLOBAL (L2-resident, 8 MiB total) -- no B LDS at all.
//      DS-pipe load drops ~40% below the MFMA-pipe time; VMEM pipe (idle)
//      absorbs B. One region per K-tile, r7's no-spill STEP/HALF interleave.

#define M_TOTAL 16384
#define E_DIM 1024
#define F_DIM 4096
#define NQ 8

typedef __attribute__((ext_vector_type(8))) short bf16x8;
typedef __attribute__((ext_vector_type(8))) unsigned short ushort8;
typedef __attribute__((ext_vector_type(4))) float f32x4;

__device__ __forceinline__ unsigned short f2bf(float f) {
  union { float f; unsigned u; } c; c.f = f;
  unsigned u = c.u + (0x7fffu + ((c.u >> 16) & 1u));
  return (unsigned short)(u >> 16);
}

// ---------------------------------------------------------------------------
__global__ __launch_bounds__(256) void w2cvt_kernel(
    const float* __restrict__ w2, unsigned short* __restrict__ w2bf) {
  size_t i = ((size_t)blockIdx.x * 256 + threadIdx.x) * 8;
  float v[8];
  *(float4*)&v[0] = *(const float4*)&w2[i];
  *(float4*)&v[4] = *(const float4*)&w2[i + 4];
  ushort8 p;
#pragma unroll
  for (int j = 0; j < 8; ++j) p[j] = f2bf(v[j]);
  *(ushort8*)&w2bf[i] = p;
}

// ---------------------------------------------------------------------------
__global__ __launch_bounds__(256) void qrelu_kernel(
    const float* __restrict__ x, const float* __restrict__ theta,
    const float* __restrict__ w1, unsigned short* __restrict__ A, int m_base) {
  __shared__ float qv[32][NQ];
  const int t = threadIdx.x;
  const int m0 = m_base + blockIdx.x * 32;
  {
    const int ml = t >> 3, q = t & 7;
    float xv = x[(size_t)(m0 + ml) * 1024 + q];
    qv[ml][q] = cosf(xv) * cosf(theta[q]);
  }
  __syncthreads();

  for (int oi = 0; oi < 2; ++oi) {
    const int o = t + oi * 256;  // f-octet index 0..511
    float w[64];
#pragma unroll
    for (int i = 0; i < 16; ++i)
      *(float4*)&w[i * 4] = *(const float4*)&w1[o * 64 + i * 4];
    for (int ml = 0; ml < 32; ++ml) {
      ushort8 pk;
#pragma unroll
      for (int j = 0; j < 8; ++j) {
        float s = 0.f;
#pragma unroll
        for (int q = 0; q < NQ; ++q) s = fmaf(qv[ml][q], w[j * 8 + q], s);
        pk[j] = f2bf(s > 0.f ? s : 0.f);
      }
      *(ushort8*)&A[(size_t)(m0 - m_base + ml) * F_DIM + o * 8] = pk;
    }
  }
}

// ---------------------------------------------------------------------------
// GEMM: BM=BN=256, BK=64, 512 thr = 8 waves (2m x 4n), wave tile 128x64.
// LDS: As [2 buf][2 half][128*64] bf16 = 64 KiB (A only). A swizzle as
// before: (row, 16B-chunk c) at phys chunk c ^ (row&7), pre-swizzled DMA
// source + XOR'd ds_read. B fragments read directly from global w2bf
// (row-major): lane reads 16 B at row (wc*64+nt*16+l15), col kt*64 +
// kk*32 + (lane>>4)*8 -- 16x 64-B segments per wave-load, L2-served.
// Region(kt), buf = kt&1:
//   [stage A(kt+1) -> buf^1 : 4 DMA]   (sched_barrier-fenced so the DMAs
//                                       stay oldest in the vmcnt queue)
//   HALF(kk=0): [4 B global loads][2 A ds_reads] then 8x STEP
//               { 1 A ds_read ahead | 4 MFMA | sched_barrier }
//   HALF(kk=1): same, B loads at offset +64 B
//   [vmcnt(0)]  -- free: only the 4 DMAs (issued ~1800 cyc ago) remain
//   [s_barrier]
// ---------------------------------------------------------------------------
#define BAR __builtin_amdgcn_s_barrier()
#define SB __builtin_amdgcn_sched_barrier(0)
#define VM0 asm volatile("s_waitcnt vmcnt(0)" ::: "memory")

#define GLDS(src, dst) \
  __builtin_amdgcn_global_load_lds( \
      (const __attribute__((address_space(1))) void*)(src), \
      (__attribute__((address_space(3))) void*)(dst), 16, 0, 0)

#define STAGE_A(buf) do { \
  GLDS(pA0, &As[buf][0][wid * 512]); \
  GLDS(pA1, &As[buf][0][4096 + wid * 512]); \
  GLDS(pA2, &As[buf][1][wid * 512]); \
  GLDS(pA3, &As[buf][1][4096 + wid * 512]); \
  pA0 += 64; pA1 += 64; pA2 += 64; pA3 += 64; \
  SB; \
} while (0)

#define RDA(buf, mt, kk) \
  (*(const bf16x8*)&asW[(buf) * 16384 + (mt) * 1024 + ((kk) ? aO1 : aO0)])

#define STEP(buf, kk, mt) do { \
  if ((mt) < 6) af3[((mt) + 2) % 3] = RDA(buf, (mt) + 2, kk); \
  __builtin_amdgcn_s_setprio(1); \
  acc[mt][0] = __builtin_amdgcn_mfma_f32_16x16x32_bf16( \
      af3[(mt) % 3], bq[0], acc[mt][0], 0, 0, 0); \
  acc[mt][1] = __builtin_amdgcn_mfma_f32_16x16x32_bf16( \
      af3[(mt) % 3], bq[1], acc[mt][1], 0, 0, 0); \
  acc[mt][2] = __builtin_amdgcn_mfma_f32_16x16x32_bf16( \
      af3[(mt) % 3], bq[2], acc[mt][2], 0, 0, 0); \
  acc[mt][3] = __builtin_amdgcn_mfma_f32_16x16x32_bf16( \
      af3[(mt) % 3], bq[3], acc[mt][3], 0, 0, 0); \
  __builtin_amdgcn_s_setprio(0); \
  SB; \
} while (0)

// OFS = 0 for kk=0, 32 elements (64 B, folds to offset imm) for kk=1.
#define HALF(buf, kk, OFS) do { \
  bf16x8 bq[4], af3[3]; \
  bq[0] = *(const bf16x8*)(pB0_ + (OFS)); \
  bq[1] = *(const bf16x8*)(pB1_ + (OFS)); \
  bq[2] = *(const bf16x8*)(pB2_ + (OFS)); \
  bq[3] = *(const bf16x8*)(pB3_ + (OFS)); \
  af3[0] = RDA(buf, 0, kk); \
  af3[1] = RDA(buf, 1, kk); \
  STEP(buf, kk, 0); STEP(buf, kk, 1); STEP(buf, kk, 2); STEP(buf, kk, 3); \
  STEP(buf, kk, 4); STEP(buf, kk, 5); STEP(buf, kk, 6); STEP(buf, kk, 7); \
} while (0)

#define REGION(buf, PREF) do { \
  if (PREF) STAGE_A((buf) ^ 1); \
  HALF(buf, 0, 0); \
  HALF(buf, 1, 32); \
  pB0_ += 64; pB1_ += 64; pB2_ += 64; pB3_ += 64; \
  VM0; \
  BAR; \
} while (0)

__global__ __launch_bounds__(512, 2) void gemm_kernel(
    const unsigned short* __restrict__ Abf, const unsigned short* __restrict__ w2bf,
    float* __restrict__ out, int m_base) {
  __shared__ __align__(16) unsigned short As[2][2][128 * 64];

  const int tid = threadIdx.x;
  const int lane = tid & 63;
  const int wid = tid >> 6;
  const int wr = wid >> 2;  // m-half of block
  const int wc = wid & 3;   // n-quarter of block

  // T1: bijective XCD-chunked swizzle (m204). Same-XCD blocks share nb so
  // each XCD's L2 holds ONE 2 MiB B-panel (B is read from global every
  // K-tile); A panels stream through LLC.
  const int nwg = gridDim.x;
  const int bid = blockIdx.x;
  const int qq = nwg >> 3, rr = nwg & 7;
  const int xcd = bid & 7, sub = bid >> 3;
  const int wgid =
      (xcd < rr ? xcd * (qq + 1) : rr * (qq + 1) + (xcd - rr) * qq) + sub;
  const int mbmax = nwg >> 2;
  const int nbk = wgid / mbmax;   // 0..3; constant across an XCD's chunk
  const int mb = wgid % mbmax;

  const unsigned short* Ag = Abf + (size_t)mb * 256 * F_DIM;

  f32x4 acc[8][4] = {};

  // --- A LDS read bases (fold to ds_read offset immediates) ---
  const int hi4 = lane >> 4, l7 = lane & 7, l15 = lane & 15;
  const int aO0 = l15 * 64 + ((hi4 ^ l7) << 3);
  const int aO1 = aO0 ^ 32;  // kk=1: chunk XOR 4
  const unsigned short* asW = &As[0][wr][0];

  // --- A stage pointers (pre-swizzled source; advance +64 elems/K-tile) ---
  const int srow = tid >> 3;              // 0..63
  const int sc = (tid & 7) ^ (srow & 7);  // source-side swizzle
  const unsigned short* pA0 = Ag + (size_t)(srow)*F_DIM + sc * 8;
  const unsigned short* pA1 = Ag + (size_t)(64 + srow) * F_DIM + sc * 8;
  const unsigned short* pA2 = Ag + (size_t)(128 + srow) * F_DIM + sc * 8;
  const unsigned short* pA3 = Ag + (size_t)(192 + srow) * F_DIM + sc * 8;

  // --- B direct-global pointers: row = nbk*256 + wc*64 + nt*16 + l15,
  //     k-offset = (lane>>4)*8; advance +64 elems per K-tile ---
  const size_t bRow = (size_t)(nbk * 256 + wc * 64 + l15);
  const unsigned short* pB0_ = w2bf + (bRow + 0) * F_DIM + hi4 * 8;
  const unsigned short* pB1_ = w2bf + (bRow + 16) * F_DIM + hi4 * 8;
  const unsigned short* pB2_ = w2bf + (bRow + 32) * F_DIM + hi4 * 8;
  const unsigned short* pB3_ = w2bf + (bRow + 48) * F_DIM + hi4 * 8;

  // --- prologue: stage A(kt0) -> buf0 ---
  STAGE_A(0);
  VM0;
  BAR;

#pragma unroll 1
  for (int t2 = 0; t2 < 31; ++t2) {
    REGION(0, 1);
    REGION(1, 1);
  }
  REGION(0, 1);
  REGION(1, 0);

  // Epilogue: C/D layout col = lane&15, row = (lane>>4)*4 + r [m89-verified]
  const int cl = lane & 15, rg = lane >> 4;
  float* ob = out + (size_t)(m_base + mb * 256 + wr * 128) * E_DIM + nbk * 256 +
              wc * 64 + cl;
#pragma unroll
  for (int mt = 0; mt < 8; ++mt)
#pragma unroll
    for (int r = 0; r < 4; ++r) {
      float* orow = ob + (size_t)(mt * 16 + rg * 4 + r) * E_DIM;
#pragma unroll
      for (int nt = 0; nt < 4; ++nt) orow[nt * 16] = acc[mt][nt][r];
    }
}

// ---------------------------------------------------------------------------
extern "C" void kernel_launch(void* const* d_in, const int* in_sizes, int n_in,
                              void* d_out, int out_size, void* d_ws, size_t ws_size,
                              hipStream_t stream) {
  const float* x = (const float*)d_in[0];
  const float* theta = (const float*)d_in[1];
  const float* w1 = (const float*)d_in[2];
  const float* w2 = (const float*)d_in[3];
  float* out = (float*)d_out;

  unsigned short* w2bf = (unsigned short*)d_ws;           // 8 MiB
  unsigned short* A = w2bf + (size_t)E_DIM * F_DIM;       // rest of ws

  size_t abytes = ws_size - (size_t)E_DIM * F_DIM * 2;
  size_t maxrows = abytes / ((size_t)F_DIM * 2);
  int Mc = (int)((maxrows / 256) * 256);
  if (Mc > M_TOTAL) Mc = M_TOTAL;
  if (Mc < 256) Mc = 256;

  w2cvt_kernel<<<E_DIM * F_DIM / 2048, 256, 0, stream>>>(w2, w2bf);

  for (int mb = 0; mb < M_TOTAL; mb += Mc) {
    int rows = M_TOTAL - mb < Mc ? M_TOTAL - mb : Mc;
    qrelu_kernel<<<rows / 32, 256, 0, stream>>>(x, theta, w1, A, mb);
    gemm_kernel<<<(rows / 256) * 4, 512, 0, stream>>>(A, w2bf, out, mb);
  }
}